// Round 2
// baseline (174.397 us; speedup 1.0000x reference)
//
#include <hip/hip_runtime.h>

typedef unsigned short ushort_t;
typedef short short8 __attribute__((ext_vector_type(8)));
typedef float f32x4 __attribute__((ext_vector_type(4)));

#define N_PTS 100000
#define NSAMP 16

__device__ __forceinline__ float b2f(ushort_t u) {
    union { unsigned int i; float f; } v; v.i = ((unsigned int)u) << 16; return v.f;
}
__device__ __forceinline__ ushort_t f2b(float f) {
    unsigned int x = __float_as_uint(f);
    unsigned int r = (x + 0x7FFFu + ((x >> 16) & 1u)) >> 16;   // RNE
    return (ushort_t)r;
}

// ---------------------------------------------------------------------------
// Kernel A: qkv[i][0..63]=q, [64..127]=k, [128..191]=v   (bf16 in workspace)
// Inputs feat/W/b are f32. Wave-per-16-point tile, MFMA 16x16x32 bf16.
// ---------------------------------------------------------------------------
__global__ __launch_bounds__(256, 4) void qkv_kernel(
    const float* __restrict__ feat,
    const float* __restrict__ Wq, const float* __restrict__ bq,
    const float* __restrict__ Wk, const float* __restrict__ bk,
    const float* __restrict__ Wv, const float* __restrict__ bv,
    ushort_t* __restrict__ qkv)
{
    const int tid  = threadIdx.x;
    const int lane = tid & 63;
    const int wid  = tid >> 6;
    const int jl   = lane & 15;   // row (A) / col (B,C)
    const int g    = lane >> 4;   // k-chunk (A,B) / row-group (C)

    const float* Ws[3] = {Wq, Wk, Wv};
    const float* bs[3] = {bq, bk, bv};

    short8 bfrag[3][4][2];
    float  bias[3][4];
#pragma unroll
    for (int m = 0; m < 3; m++)
#pragma unroll
        for (int cb = 0; cb < 4; cb++) {
#pragma unroll
            for (int h = 0; h < 2; h++) {
                short8 f;
#pragma unroll
                for (int e = 0; e < 8; e++)
                    f[e] = (short)f2b(Ws[m][(h * 32 + g * 8 + e) * 64 + cb * 16 + jl]);
                bfrag[m][cb][h] = f;
            }
            bias[m][cb] = bs[m][cb * 16 + jl];
        }

    const int nwaves = gridDim.x * (blockDim.x >> 6);
    const int gw     = blockIdx.x * (blockDim.x >> 6) + wid;
    const int ntiles = N_PTS / 16;   // 6250, exact

    for (int t = gw; t < ntiles; t += nwaves) {
        const int i0 = t * 16;
        const float* arow = feat + (i0 + jl) * 64;
        const f32x4 a00 = *(const f32x4*)(arow + g * 8);
        const f32x4 a01 = *(const f32x4*)(arow + g * 8 + 4);
        const f32x4 a10 = *(const f32x4*)(arow + 32 + g * 8);
        const f32x4 a11 = *(const f32x4*)(arow + 32 + g * 8 + 4);
        short8 a0, a1;
#pragma unroll
        for (int e = 0; e < 4; e++) {
            a0[e]     = (short)f2b(a00[e]);
            a0[4 + e] = (short)f2b(a01[e]);
            a1[e]     = (short)f2b(a10[e]);
            a1[4 + e] = (short)f2b(a11[e]);
        }
#pragma unroll
        for (int m = 0; m < 3; m++)
#pragma unroll
            for (int cb = 0; cb < 4; cb++) {
                f32x4 acc = {0.f, 0.f, 0.f, 0.f};
                acc = __builtin_amdgcn_mfma_f32_16x16x32_bf16(a0, bfrag[m][cb][0], acc, 0, 0, 0);
                acc = __builtin_amdgcn_mfma_f32_16x16x32_bf16(a1, bfrag[m][cb][1], acc, 0, 0, 0);
#pragma unroll
                for (int r = 0; r < 4; r++) {
                    const int row = i0 + g * 4 + r;           // C: row=(lane>>4)*4+reg
                    qkv[row * 192 + m * 64 + cb * 16 + jl] = f2b(acc[r] + bias[m][cb]);
                }
            }
    }
}

// ---------------------------------------------------------------------------
// Kernel B: fused attention, one wave per point.
// lane = (j = lane&15 neighbor, g = lane>>4); lane's channels: {g*8..g*8+7} and
// {32+g*8..32+g*8+7} (the two k-halves of the 16x16x32 MFMA).
// ---------------------------------------------------------------------------
__global__ __launch_bounds__(256, 2) void attn_kernel(
    const float* __restrict__ point, const int* __restrict__ idx,
    const ushort_t* __restrict__ qkv,
    const float* pW1, const float* pb1, const float* pg1, const float* pbe1,
    const float* pm1, const float* pv1, const float* pW2, const float* pb2,
    const float* wg1, const float* wbe1, const float* wm1, const float* wv1,
    const float* wW1, const float* wb1, const float* wg2, const float* wbe2,
    const float* wm2, const float* wv2, const float* wW2, const float* wb2,
    float* __restrict__ out)
{
    __shared__ float lds[4][2][128];   // per-wave 2x 16x8 f32 transpose buffers

    const int tid  = threadIdx.x;
    const int lane = tid & 63;
    const int wid  = tid >> 6;
    const int jl   = lane & 15;
    const int g    = lane >> 4;

    // --- runtime idx dtype probe: int64 iff the 16 odd int32 words are all 0 ---
    int zp = 0;
#pragma unroll
    for (int k = 0; k < 16; k++) zp |= idx[2 * k + 1];
    const bool idx64 = (zp == 0);

    // --- linear_p layer 1 (3x3 + BN folded), uniform across lanes ---
    float A1s[3][3], c1[3];
#pragma unroll
    for (int u = 0; u < 3; u++) {
        const float s = pg1[u] * rsqrtf(pv1[u] + 1e-5f);
        c1[u] = (pb1[u] - pm1[u]) * s + pbe1[u];
#pragma unroll
        for (int t = 0; t < 3; t++) A1s[t][u] = pW1[t * 3 + u] * s;
    }
    // --- per-channel constants for this lane's 16 channels ---
    float pw2c[2][3][8], pb2c[2][8], bn1s[2][8], bn1b[2][8];
#pragma unroll
    for (int h = 0; h < 2; h++)
#pragma unroll
        for (int e = 0; e < 8; e++) {
            const int c = h * 32 + g * 8 + e;
#pragma unroll
            for (int t = 0; t < 3; t++) pw2c[h][t][e] = pW2[t * 64 + c];
            pb2c[h][e] = pb2[c];
            const float s = wg1[c] * rsqrtf(wv1[c] + 1e-5f);
            bn1s[h][e] = s;
            bn1b[h][e] = wbe1[c] - wm1[c] * s;
        }
    // --- W1 B-frag (cols 8..15 zero-padded) ---
    short8 w1f[2];
#pragma unroll
    for (int h = 0; h < 2; h++)
#pragma unroll
        for (int e = 0; e < 8; e++)
            w1f[h][e] = (jl < 8) ? (short)f2b(wW1[(h * 32 + g * 8 + e) * 8 + jl]) : (short)0;
    const float b1o  = (jl < 8) ? wb1[jl] : 0.f;
    const float bn2s = (jl < 8) ? wg2[jl] * rsqrtf(wv2[jl] + 1e-5f) : 0.f;
    const float bn2b = (jl < 8) ? wbe2[jl] - wm2[jl] * bn2s : 0.f;
    // --- W2 B-frag for mfma#3 (K padded to 32 with zeros) ---
    short8 w2f;
#pragma unroll
    for (int e = 0; e < 8; e++)
        w2f[e] = (g == 0 && jl < 8) ? (short)f2b(wW2[e * 8 + jl]) : (short)0;
    const float b2o = (jl < 8) ? wb2[jl] : 0.f;

    const int nwaves = gridDim.x * (blockDim.x >> 6);
    const int gw     = blockIdx.x * (blockDim.x >> 6) + wid;
    float* l1 = lds[wid][0];
    float* l2 = lds[wid][1];

    for (int i = gw; i < N_PTS; i += nwaves) {
        int nb;
        if (idx64) nb = idx[(i * NSAMP + jl) * 2];
        else       nb = idx[i * NSAMP + jl];

        // issue all gathers up front
        const float px0 = point[i * 3 + 0];
        const float px1 = point[i * 3 + 1];
        const float px2 = point[i * 3 + 2];
        const float nx0 = point[nb * 3 + 0];
        const float nx1 = point[nb * 3 + 1];
        const float nx2 = point[nb * 3 + 2];
        const short8 fq0 = *(const short8*)(qkv + i * 192 + g * 8);
        const short8 fq1 = *(const short8*)(qkv + i * 192 + 32 + g * 8);
        const short8 gk0 = *(const short8*)(qkv + nb * 192 + 64 + g * 8);
        const short8 gk1 = *(const short8*)(qkv + nb * 192 + 96 + g * 8);
        const short8 gv0 = *(const short8*)(qkv + nb * 192 + 128 + g * 8);
        const short8 gv1 = *(const short8*)(qkv + nb * 192 + 160 + g * 8);

        // position-encoding MLP (f32)
        const float d0 = nx0 - px0, d1 = nx1 - px1, d2 = nx2 - px2;
        float y[3];
#pragma unroll
        for (int u = 0; u < 3; u++)
            y[u] = fmaxf(d0 * A1s[0][u] + d1 * A1s[1][u] + d2 * A1s[2][u] + c1[u], 0.f);
        float pr[2][8];
#pragma unroll
        for (int h = 0; h < 2; h++)
#pragma unroll
            for (int e = 0; e < 8; e++)
                pr[h][e] = pb2c[h][e] + y[0] * pw2c[h][0][e] + y[1] * pw2c[h][1][e]
                         + y[2] * pw2c[h][2][e];

        // w = relu(bn1(gk - fq + pr)) -> bf16 A-frags
        short8 af0, af1;
#pragma unroll
        for (int e = 0; e < 8; e++) {
            float w0 = b2f((ushort_t)gk0[e]) - b2f((ushort_t)fq0[e]) + pr[0][e];
            w0 = fmaxf(w0 * bn1s[0][e] + bn1b[0][e], 0.f);
            af0[e] = (short)f2b(w0);
            float w1 = b2f((ushort_t)gk1[e]) - b2f((ushort_t)fq1[e]) + pr[1][e];
            w1 = fmaxf(w1 * bn1s[1][e] + bn1b[1][e], 0.f);
            af1[e] = (short)f2b(w1);
        }
        // u[j][o] = w @ W1  (16x8, K=64 in two MFMAs)
        f32x4 u = {0.f, 0.f, 0.f, 0.f};
        u = __builtin_amdgcn_mfma_f32_16x16x32_bf16(af0, w1f[0], u, 0, 0, 0);
        u = __builtin_amdgcn_mfma_f32_16x16x32_bf16(af1, w1f[1], u, 0, 0, 0);

        // +b1, bn2, relu in C-layout, then transpose C->A via LDS
        if (jl < 8) {
#pragma unroll
            for (int r = 0; r < 4; r++) {
                const float ur = fmaxf((u[r] + b1o) * bn2s + bn2b, 0.f);
                l1[(g * 4 + r) * 8 + jl] = ur;
            }
        }
        __builtin_amdgcn_wave_barrier();
        short8 aU = {0, 0, 0, 0, 0, 0, 0, 0};
        if (g == 0) {
#pragma unroll
            for (int e = 0; e < 8; e++) aU[e] = (short)f2b(l1[jl * 8 + e]);
        }
        // u2[j][o'] = relu'd u @ W2 (16x8, K=8 zero-padded)
        f32x4 u2 = {0.f, 0.f, 0.f, 0.f};
        u2 = __builtin_amdgcn_mfma_f32_16x16x32_bf16(aU, w2f, u2, 0, 0, 0);

        // softmax over the 16 neighbors (in-lane 4 regs + xor16/32), per col o'=jl
        const float x0 = u2[0] + b2o, x1 = u2[1] + b2o, x2 = u2[2] + b2o, x3 = u2[3] + b2o;
        float m = fmaxf(fmaxf(x0, x1), fmaxf(x2, x3));
        m = fmaxf(m, __shfl_xor(m, 16, 64));
        m = fmaxf(m, __shfl_xor(m, 32, 64));
        const float e0 = __expf(x0 - m), e1 = __expf(x1 - m);
        const float e2 = __expf(x2 - m), e3 = __expf(x3 - m);
        float s = e0 + e1 + e2 + e3;
        s += __shfl_xor(s, 16, 64);
        s += __shfl_xor(s, 32, 64);
        const float inv = 1.0f / s;

        // redistribute wnorm[j][0..7] to lanes with j = jl via LDS
        if (jl < 8) {
            l2[(g * 4 + 0) * 8 + jl] = e0 * inv;
            l2[(g * 4 + 1) * 8 + jl] = e1 * inv;
            l2[(g * 4 + 2) * 8 + jl] = e2 * inv;
            l2[(g * 4 + 3) * 8 + jl] = e3 * inv;
        }
        __builtin_amdgcn_wave_barrier();
        float wl[8];
#pragma unroll
        for (int e = 0; e < 8; e++) wl[e] = l2[jl * 8 + e];

        // PV: out[c] = sum_j (gv + pr)[j][c] * wnorm[j][c&7]
        float po[2][8];
#pragma unroll
        for (int e = 0; e < 8; e++) {
            po[0][e] = (b2f((ushort_t)gv0[e]) + pr[0][e]) * wl[e];
            po[1][e] = (b2f((ushort_t)gv1[e]) + pr[1][e]) * wl[e];
        }
#pragma unroll
        for (int mask = 1; mask < 16; mask <<= 1)
#pragma unroll
            for (int h = 0; h < 2; h++)
#pragma unroll
                for (int e = 0; e < 8; e++)
                    po[h][e] += __shfl_xor(po[h][e], mask, 64);

        if (jl == 0) {
            f32x4 oa, ob, oc, od;
#pragma unroll
            for (int e = 0; e < 4; e++) {
                oa[e] = po[0][e];
                ob[e] = po[0][4 + e];
                oc[e] = po[1][e];
                od[e] = po[1][4 + e];
            }
            *(f32x4*)(out + i * 64 + g * 8)          = oa;
            *(f32x4*)(out + i * 64 + g * 8 + 4)      = ob;
            *(f32x4*)(out + i * 64 + 32 + g * 8)     = oc;
            *(f32x4*)(out + i * 64 + 32 + g * 8 + 4) = od;
        }
    }
}

extern "C" void kernel_launch(void* const* d_in, const int* in_sizes, int n_in,
                              void* d_out, int out_size, void* d_ws, size_t ws_size,
                              hipStream_t stream) {
    const float* point = (const float*)d_in[0];
    const float* feat  = (const float*)d_in[1];
    const int*   idx   = (const int*)d_in[2];
    const float* Wq = (const float*)d_in[3];  const float* bq = (const float*)d_in[4];
    const float* Wk = (const float*)d_in[5];  const float* bk = (const float*)d_in[6];
    const float* Wv = (const float*)d_in[7];  const float* bv = (const float*)d_in[8];
    const float* pW1  = (const float*)d_in[9];
    const float* pb1  = (const float*)d_in[10];
    const float* pg1  = (const float*)d_in[11];
    const float* pbe1 = (const float*)d_in[12];
    const float* pm1  = (const float*)d_in[13];
    const float* pv1  = (const float*)d_in[14];
    const float* pW2  = (const float*)d_in[15];
    const float* pb2  = (const float*)d_in[16];
    const float* wg1  = (const float*)d_in[17];
    const float* wbe1 = (const float*)d_in[18];
    const float* wm1  = (const float*)d_in[19];
    const float* wv1  = (const float*)d_in[20];
    const float* wW1  = (const float*)d_in[21];
    const float* wb1  = (const float*)d_in[22];
    const float* wg2  = (const float*)d_in[23];
    const float* wbe2 = (const float*)d_in[24];
    const float* wm2  = (const float*)d_in[25];
    const float* wv2  = (const float*)d_in[26];
    const float* wW2  = (const float*)d_in[27];
    const float* wb2  = (const float*)d_in[28];

    ushort_t* qkv  = (ushort_t*)d_ws;            // 100000*192*2B = 38.4 MB
    float*    outp = (float*)d_out;

    hipLaunchKernelGGL(qkv_kernel, dim3(512), dim3(256), 0, stream,
                       feat, Wq, bq, Wk, bk, Wv, bv, qkv);
    hipLaunchKernelGGL(attn_kernel, dim3(1024), dim3(256), 0, stream,
                       point, idx, qkv,
                       pW1, pb1, pg1, pbe1, pm1, pv1, pW2, pb2,
                       wg1, wbe1, wm1, wv1, wW1, wb1,
                       wg2, wbe2, wm2, wv2, wW2, wb2,
                       outp);
}